// Round 1
// 531.472 us; speedup vs baseline: 1.0918x; 1.0918x over previous
//
#include <hip/hip_runtime.h>
#include <cstdint>
#include <cstddef>

typedef _Float16 half8 __attribute__((ext_vector_type(8)));
typedef _Float16 half4 __attribute__((ext_vector_type(4)));
typedef float f32x4 __attribute__((ext_vector_type(4)));

// async global->LDS, 16B per lane; LDS dest must be wave-uniform base + lane*16
#define GLDS16(g, l) __builtin_amdgcn_global_load_lds( \
    (__attribute__((address_space(1))) void*)(g), \
    (__attribute__((address_space(3))) void*)(l), 16, 0, 0)

// ---------------------------------------------------------------------------
// fp32 -> fp16 convert
// ---------------------------------------------------------------------------
__global__ __launch_bounds__(256) void cvt_f32_f16(const float* __restrict__ src,
                                                   _Float16* __restrict__ dst, int n) {
  int i = (blockIdx.x * 256 + threadIdx.x) * 8;
  if (i >= n) return;
  float4 a = *(const float4*)(src + i);
  float4 b = *(const float4*)(src + i + 4);
  half8 h;
  h[0] = (_Float16)a.x; h[1] = (_Float16)a.y; h[2] = (_Float16)a.z; h[3] = (_Float16)a.w;
  h[4] = (_Float16)b.x; h[5] = (_Float16)b.y; h[6] = (_Float16)b.z; h[7] = (_Float16)b.w;
  *(half8*)(dst + i) = h;
}

// ---------------------------------------------------------------------------
// GEMM C[m,n] = sum_k A[m,k]*Bw[n,k] (+bias).  A fp16 MxK, Bw fp16 NxK, K=512.
// 128x128 tile, BK=32, 4 waves 2x2, each wave 4x4 16x16x32 MFMAs.
// LDS tiles in MFMA FRAGMENT ORDER (slot c*16+r within a 16-row band) so both
// the global_load_lds writes and fragment ds_read_b128 are base + lane*16.
//
// Pipeline (T3/T4 minimal): 3 LDS buffers, depth-2 prefetch. Each iter k:
//   s_waitcnt vmcnt(4)        <- tile k landed; tile k+1's 4 loads STAY IN FLIGHT
//   s_barrier                 <- raw barrier (no implicit vmcnt(0) drain!)
//   stage tile k+2 -> buf[(k+2)%3]   (that buffer was last read at iter k-1)
//   ds_read frags of buf[k%3]; 16 MFMA
// The counted vmcnt is the whole point: __syncthreads() would drain the
// global_load_lds queue (vmcnt(0)) and re-expose full load latency per iter.
// ---------------------------------------------------------------------------
template<int NOUT, int NT, bool BIAS>
__global__ __launch_bounds__(256, 3) void gemm_bt(const _Float16* __restrict__ A,
                                                  const _Float16* __restrict__ Bw,
                                                  const float* __restrict__ bias,
                                                  void* __restrict__ Cout) {
  constexpr int K = 512;
  constexpr int NIT = K / 32;      // 16 K-steps
  __shared__ union {
    _Float16 S[3][2][4096];        // [buf][A=0/B=1][fragment-order 128x32 tile]
    float E[2][16][132];           // epilogue staging
  } u;
  const int id  = blockIdx.x;
  const int xcd = id & 7;                 // XCD cohort: N-tiles of a band share L2
  const int jj  = id >> 3;
  const int by  = (jj / NT) * 8 + xcd;
  const int bx  = jj % NT;
  const int m_base = by * 128, n_base = bx * 128;

  const int t    = threadIdx.x;
  const int lane = t & 63;
  const int wid  = t >> 6;
  const int wm   = wid >> 1, wn = wid & 1;
  const int cl   = lane & 15, q = lane >> 4;

  f32x4 acc[4][4] = {};

  // staging: thread t owns slots t and t+256.
  // slot s -> band = s>>6 (16 rows), k-chunk c = (s>>4)&3, row r = s&15
  const int s0 = t, s1 = t + 256;
  const int r0 = ((s0 >> 6) << 4) | (s0 & 15), c0 = (s0 >> 4) & 3;
  const int r1 = ((s1 >> 6) << 4) | (s1 & 15), c1 = (s1 >> 4) & 3;
  const _Float16* a0 = A  + (size_t)(m_base + r0) * K + c0 * 8;
  const _Float16* a1 = A  + (size_t)(m_base + r1) * K + c1 * 8;
  const _Float16* b0 = Bw + (size_t)(n_base + r0) * K + c0 * 8;
  const _Float16* b1 = Bw + (size_t)(n_base + r1) * K + c1 * 8;

  const int lane8 = lane * 8;   // fragment offset in halves within a band

  auto stage = [&](int kt, int b) {
    const int ko = kt * 32;
    GLDS16(a0 + ko, (char*)&u.S[b][0][0] + s0 * 16);
    GLDS16(a1 + ko, (char*)&u.S[b][0][0] + s1 * 16);
    GLDS16(b0 + ko, (char*)&u.S[b][1][0] + s0 * 16);
    GLDS16(b1 + ko, (char*)&u.S[b][1][0] + s1 * 16);
  };

  stage(0, 0);
  stage(1, 1);

#pragma unroll
  for (int k = 0; k < NIT; ++k) {
    // wait tile k (oldest 4 loads); keep tile k+1's 4 loads in flight
    if (k < NIT - 1) asm volatile("s_waitcnt vmcnt(4)" ::: "memory");
    else             asm volatile("s_waitcnt vmcnt(0)" ::: "memory");
    __builtin_amdgcn_s_barrier();
    asm volatile("" ::: "memory");   // no LDS access hoisted above the barrier
    if (k < NIT - 2) stage(k + 2, (k + 2) % 3);

    const _Float16* As = &u.S[k % 3][0][0];
    const _Float16* Bs = &u.S[k % 3][1][0];
    half8 af[4], bf[4];
#pragma unroll
    for (int i = 0; i < 4; i++) af[i] = *(const half8*)(As + (wm * 4 + i) * 512 + lane8);
#pragma unroll
    for (int i = 0; i < 4; i++) bf[i] = *(const half8*)(Bs + (wn * 4 + i) * 512 + lane8);
#pragma unroll
    for (int mt = 0; mt < 4; mt++)
#pragma unroll
      for (int nt = 0; nt < 4; nt++)
        acc[mt][nt] = __builtin_amdgcn_mfma_f32_16x16x32_f16(af[mt], bf[nt], acc[mt][nt], 0, 0, 0);
  }
  __syncthreads();   // all waves done with S before E overlays it

  // epilogue: C/D layout (row=q*4+r, col=lane&15) -> LDS -> group-aligned reads
  const int ebnd = t >> 7, erow = (t >> 3) & 15, ecs = t & 7;
#pragma unroll
  for (int mt = 0; mt < 4; mt++) {
#pragma unroll
    for (int nt = 0; nt < 4; nt++)
#pragma unroll
      for (int r = 0; r < 4; r++)
        u.E[wm][q * 4 + r][wn * 64 + nt * 16 + cl] = acc[mt][nt][r];
    __syncthreads();
    const size_t rg = (size_t)(m_base + ebnd * 64 + mt * 16 + erow);
#pragma unroll
    for (int j = 0; j < 4; j++) {
      // E row stride = 132 floats = 33 chunks -> bank group = (erow + chunk) & 7.
      // chunk = ((ecs - erow) & 7) + 8j  =>  group = ecs = lane&7 (conflict-free)
      const int ch = ((ecs - erow) & 7) + 8 * j;
      const int cc = ch * 4;
      float4 e = *(const float4*)&u.E[ebnd][erow][cc];
      if constexpr (BIAS) {
        const float4 bb = *(const float4*)(bias + n_base + cc);
        e.x += bb.x; e.y += bb.y; e.z += bb.z; e.w += bb.w;
        *(float4*)((float*)Cout + rg * NOUT + n_base + cc) = e;
      } else {
        half4 hv;
        hv[0] = (_Float16)e.x; hv[1] = (_Float16)e.y;
        hv[2] = (_Float16)e.z; hv[3] = (_Float16)e.w;
        *(half4*)((_Float16*)Cout + rg * NOUT + n_base + cc) = hv;
      }
    }
    __syncthreads();
  }
}

// ---------------------------------------------------------------------------
// Windowed attention: one block per (head h, window b). W=64, hd=64.
// QKV rows: token = b*64+w; cols: q=h*64+e, k=512+h*64+e, v=1024+h*64+e.
// Q/K staged in fragment order: band (16 rows) x 8 chunks; chunk (r,c) of a
// band at slot c*16 + r  ->  fragment reads are band_base + lane*16.
// ---------------------------------------------------------------------------
__global__ __launch_bounds__(256, 3) void attn_win(const _Float16* __restrict__ QKV,
                                                   _Float16* __restrict__ Out) {
  __shared__ _Float16 Qs[4096];
  __shared__ _Float16 Ks[4096];
  __shared__ _Float16 Vt[64][72];   // V transposed: Vt[e][j], padded rows
  __shared__ _Float16 Ps[64][72];   // softmax probs
  __shared__ _Float16 Os[64][72];   // output staging
  const int h = blockIdx.x, b = blockIdx.y;
  const int t = threadIdx.x;
  const int lane = t & 63, wid = t >> 6;
  const int cl = lane & 15, q = lane >> 4;

  // ---- stage Q,K (async, fragment order) and V (manual transpose) ----
  {
    // slot s -> band = s>>7 (16 rows), chunk c = (s>>4)&7, row r = s&15
    const int s0 = t, s1 = t + 256;
    const int r0 = ((s0 >> 7) << 4) | (s0 & 15), ch0 = (s0 >> 4) & 7;
    const int r1 = ((s1 >> 7) << 4) | (s1 & 15), ch1 = (s1 >> 4) & 7;
    const _Float16* g0 = QKV + (size_t)(b * 64 + r0) * 1536 + h * 64 + ch0 * 8;
    const _Float16* g1 = QKV + (size_t)(b * 64 + r1) * 1536 + h * 64 + ch1 * 8;
    GLDS16(g0,       (char*)Qs + s0 * 16);
    GLDS16(g1,       (char*)Qs + s1 * 16);
    GLDS16(g0 + 512, (char*)Ks + s0 * 16);
    GLDS16(g1 + 512, (char*)Ks + s1 * 16);

    const int vj = t & 63, vp = t >> 6;   // row j of V, 16-half chunk vp
    const _Float16* vsrc = QKV + (size_t)(b * 64 + vj) * 1536 + 1024 + h * 64 + vp * 16;
    half8 v0 = *(const half8*)vsrc;
    half8 v1 = *(const half8*)(vsrc + 8);
#pragma unroll
    for (int i = 0; i < 8; i++) Vt[vp * 16 + i][vj] = v0[i];
#pragma unroll
    for (int i = 0; i < 8; i++) Vt[vp * 16 + 8 + i][vj] = v1[i];
  }
  __syncthreads();

  const int m0 = wid * 16;      // wave's 16 query rows
  const int lane8 = lane * 8;   // fragment offset in halves within a band

  // ---- S = Q K^T ----
  f32x4 s[4] = {};
#pragma unroll
  for (int ks = 0; ks < 2; ks++) {
    half8 a = *(const half8*)(Qs + wid * 1024 + ks * 512 + lane8);
#pragma unroll
    for (int nt = 0; nt < 4; nt++) {
      half8 bb = *(const half8*)(Ks + nt * 1024 + ks * 512 + lane8);
      s[nt] = __builtin_amdgcn_mfma_f32_16x16x32_f16(a, bb, s[nt], 0, 0, 0);
    }
  }

  // ---- softmax over 64 keys per row (row=q*4+r, keys spread over cl x nt) ----
  constexpr float SC = 0.125f * 1.44269504088896340736f;  // scale * log2(e)
#pragma unroll
  for (int r = 0; r < 4; r++) {
    float mx = fmaxf(fmaxf(s[0][r], s[1][r]), fmaxf(s[2][r], s[3][r]));
    mx = fmaxf(mx, __shfl_xor(mx, 1));
    mx = fmaxf(mx, __shfl_xor(mx, 2));
    mx = fmaxf(mx, __shfl_xor(mx, 4));
    mx = fmaxf(mx, __shfl_xor(mx, 8));
    float e[4], ssum = 0.f;
#pragma unroll
    for (int nt = 0; nt < 4; nt++) { e[nt] = exp2f((s[nt][r] - mx) * SC); ssum += e[nt]; }
    ssum += __shfl_xor(ssum, 1);
    ssum += __shfl_xor(ssum, 2);
    ssum += __shfl_xor(ssum, 4);
    ssum += __shfl_xor(ssum, 8);
    float inv = 1.f / ssum;
    const int row = m0 + q * 4 + r;
#pragma unroll
    for (int nt = 0; nt < 4; nt++) Ps[row][nt * 16 + cl] = (_Float16)(e[nt] * inv);
  }
  __syncthreads();

  // ---- O = P V  (a: Ps rows; b: Vt rows = V columns; 72-pad rotates groups) ----
  f32x4 o[4] = {};
#pragma unroll
  for (int ks = 0; ks < 2; ks++) {
    half8 a = *(const half8*)&Ps[m0 + cl][ks * 32 + q * 8];
#pragma unroll
    for (int nt = 0; nt < 4; nt++) {
      half8 bb = *(const half8*)&Vt[nt * 16 + cl][ks * 32 + q * 8];
      o[nt] = __builtin_amdgcn_mfma_f32_16x16x32_f16(a, bb, o[nt], 0, 0, 0);
    }
  }
#pragma unroll
  for (int nt = 0; nt < 4; nt++)
#pragma unroll
    for (int r = 0; r < 4; r++)
      Os[m0 + q * 4 + r][nt * 16 + cl] = (_Float16)o[nt][r];
  __syncthreads();

  // ---- coalesced write-out ----
  {
    const int row = t >> 2, cs = t & 3;
    half8 h0 = *(const half8*)&Os[row][cs * 16];
    half8 h1 = *(const half8*)&Os[row][cs * 16 + 8];
    _Float16* dst = Out + (size_t)(b * 64 + row) * 512 + h * 64 + cs * 16;
    *(half8*)dst = h0;
    *((half8*)dst + 1) = h1;
  }
}

// ---------------------------------------------------------------------------
extern "C" void kernel_launch(void* const* d_in, const int* in_sizes, int n_in,
                              void* d_out, int out_size, void* d_ws, size_t ws_size,
                              hipStream_t stream) {
  const float* x      = (const float*)d_in[0];   // 16*4096*512
  const float* qkv_w  = (const float*)d_in[1];   // 1536*512
  const float* proj_w = (const float*)d_in[2];   // 512*512
  const float* proj_b = (const float*)d_in[3];   // 512
  float* out = (float*)d_out;

  char* ws = (char*)d_ws;
  _Float16* QKVh = (_Float16*)ws;                 // 65536*1536 fp16 = 201,326,592 B
  _Float16* Xh   = (_Float16*)(ws + 201326592);   // 65536*512 fp16 = 67,108,864 B
  _Float16* Outh = Xh;                            // alias: Xh dead after qkv_gemm
  _Float16* Wq   = (_Float16*)(ws + 268435456);   // 1536*512 fp16
  _Float16* Wp   = (_Float16*)(ws + 270008320);   // 512*512 fp16

  cvt_f32_f16<<<16384, 256, 0, stream>>>(x, Xh, 16 * 4096 * 512);
  cvt_f32_f16<<<384, 256, 0, stream>>>(qkv_w, Wq, 1536 * 512);
  cvt_f32_f16<<<128, 256, 0, stream>>>(proj_w, Wp, 512 * 512);
  gemm_bt<1536, 12, false><<<6144, 256, 0, stream>>>(Xh, Wq, nullptr, QKVh);
  attn_win<<<dim3(8, 1024), 256, 0, stream>>>(QKVh, Outh);
  gemm_bt<512, 4, true><<<2048, 256, 0, stream>>>(Outh, Wp, proj_b, out);
}

// Round 2
// 480.007 us; speedup vs baseline: 1.2089x; 1.1072x over previous
//
#include <hip/hip_runtime.h>
#include <cstdint>
#include <cstddef>

typedef _Float16 half8 __attribute__((ext_vector_type(8)));
typedef _Float16 half4 __attribute__((ext_vector_type(4)));
typedef float f32x4 __attribute__((ext_vector_type(4)));

// async global->LDS, 16B per lane; LDS dest must be wave-uniform base + lane*16
#define GLDS16(g, l) __builtin_amdgcn_global_load_lds( \
    (__attribute__((address_space(1))) void*)(g), \
    (__attribute__((address_space(3))) void*)(l), 16, 0, 0)

// ---------------------------------------------------------------------------
// fp32 -> fp16 convert
// ---------------------------------------------------------------------------
__global__ __launch_bounds__(256) void cvt_f32_f16(const float* __restrict__ src,
                                                   _Float16* __restrict__ dst, int n) {
  int i = (blockIdx.x * 256 + threadIdx.x) * 8;
  if (i >= n) return;
  float4 a = *(const float4*)(src + i);
  float4 b = *(const float4*)(src + i + 4);
  half8 h;
  h[0] = (_Float16)a.x; h[1] = (_Float16)a.y; h[2] = (_Float16)a.z; h[3] = (_Float16)a.w;
  h[4] = (_Float16)b.x; h[5] = (_Float16)b.y; h[6] = (_Float16)b.z; h[7] = (_Float16)b.w;
  *(half8*)(dst + i) = h;
}

// ---------------------------------------------------------------------------
// GEMM C[m,n] = sum_k A[m,k]*Bw[n,k] (+bias).  A fp16 MxK, Bw fp16 NxK, K=512.
// 256x256 tile, BK=32, 8 waves (2M x 4N), wave tile 128x64 (8x4 16x16x32 MFMAs).
// Rationale: LDS-read-BW bound. Wave-tile intensity = a*b/(a+b) FLOP per LDS
// byte; 64x64 gave 32 (measured MfmaUtil 21% == MFMA-cy/LDS-cy), 128x64 gives
// 42.7 and raises MFMA work per CU-iter 192->256 while LDS traffic drops.
//
// LDS tiles in MFMA FRAGMENT ORDER (slot c*16+r within a 16-row band) so both
// the global_load_lds writes and fragment ds_read_b128 are base + lane*16.
//
// Pipeline: 3 LDS buffers, depth-2 prefetch, counted vmcnt (never 0 in loop):
//   s_waitcnt vmcnt(4); s_barrier; stage(k+2); ds_read buf[k%3]; 32 MFMA
// ---------------------------------------------------------------------------
template<int NOUT, int NT, bool BIAS>
__global__ __launch_bounds__(512, 2) void gemm_bt(const _Float16* __restrict__ A,
                                                  const _Float16* __restrict__ Bw,
                                                  const float* __restrict__ bias,
                                                  void* __restrict__ Cout) {
  constexpr int K = 512;
  constexpr int NIT = K / 32;      // 16 K-steps
  __shared__ union {
    _Float16 S[3][2][8192];        // [buf][A=0/B=1][fragment-order 256x32 tile]
    float E[2][16][264];           // epilogue staging: 2 bands x 16 rows x 256(+8)
  } u;
  const int id  = blockIdx.x;
  const int xcd = id & 7;                 // XCD cohort: N-tiles of a band share L2
  const int jj  = id >> 3;
  const int by  = (jj / NT) * 8 + xcd;
  const int bx  = jj % NT;
  const int m_base = by * 256, n_base = bx * 256;

  const int t    = threadIdx.x;    // 0..511
  const int lane = t & 63;
  const int wid  = t >> 6;         // 0..7
  const int wm   = wid & 1;        // M half: rows wm*128 .. wm*128+127
  const int wn   = wid >> 1;       // N quarter: cols wn*64 .. wn*64+63
  const int cl   = lane & 15, q = lane >> 4;

  f32x4 acc[8][4] = {};

  // staging: thread t owns slots t and t+512 of each 1024-slot tile.
  // slot s -> band = s>>6 (16 rows), k-chunk c = (s>>4)&3, row r = s&15
  const int s0 = t, s1 = t + 512;
  const int r0 = ((s0 >> 6) << 4) | (s0 & 15), c0 = (s0 >> 4) & 3;
  const int r1 = ((s1 >> 6) << 4) | (s1 & 15), c1 = (s1 >> 4) & 3;
  const _Float16* a0 = A  + (size_t)(m_base + r0) * K + c0 * 8;
  const _Float16* a1 = A  + (size_t)(m_base + r1) * K + c1 * 8;
  const _Float16* b0 = Bw + (size_t)(n_base + r0) * K + c0 * 8;
  const _Float16* b1 = Bw + (size_t)(n_base + r1) * K + c1 * 8;

  const int lane8 = lane * 8;   // fragment offset in halves within a band

  auto stage = [&](int kt, int b) {
    const int ko = kt * 32;
    GLDS16(a0 + ko, (char*)&u.S[b][0][0] + s0 * 16);
    GLDS16(a1 + ko, (char*)&u.S[b][0][0] + s1 * 16);
    GLDS16(b0 + ko, (char*)&u.S[b][1][0] + s0 * 16);
    GLDS16(b1 + ko, (char*)&u.S[b][1][0] + s1 * 16);
  };

  stage(0, 0);
  stage(1, 1);

#pragma unroll
  for (int k = 0; k < NIT; ++k) {
    // wait tile k (oldest 4 loads); keep tile k+1's 4 loads in flight
    if (k < NIT - 1) asm volatile("s_waitcnt vmcnt(4)" ::: "memory");
    else             asm volatile("s_waitcnt vmcnt(0)" ::: "memory");
    __builtin_amdgcn_s_barrier();
    asm volatile("" ::: "memory");   // no LDS access hoisted above the barrier
    if (k < NIT - 2) stage(k + 2, (k + 2) % 3);

    const _Float16* As = &u.S[k % 3][0][0];
    const _Float16* Bs = &u.S[k % 3][1][0];
    half8 af[8], bf[4];
#pragma unroll
    for (int i = 0; i < 8; i++) af[i] = *(const half8*)(As + (wm * 8 + i) * 512 + lane8);
#pragma unroll
    for (int i = 0; i < 4; i++) bf[i] = *(const half8*)(Bs + (wn * 4 + i) * 512 + lane8);
#pragma unroll
    for (int mt = 0; mt < 8; mt++)
#pragma unroll
      for (int nt = 0; nt < 4; nt++)
        acc[mt][nt] = __builtin_amdgcn_mfma_f32_16x16x32_f16(af[mt], bf[nt], acc[mt][nt], 0, 0, 0);
  }
  __syncthreads();   // all waves done with S before E overlays it

  // epilogue: round j stages band j (wm=0 waves) and band 8+j (wm=1 waves);
  // acc index == j is compile-time under the unroll.
  // E row stride = 264 floats = 66 chunks -> read bank group = (2*erow+ecs)&7,
  // distinct within each lane octet -> conflict-free.
  const int eb = t >> 8;            // which of the 2 staged bands
  const int erow = (t >> 4) & 15;   // row within band
  const int ecs = t & 15;           // 16 threads per row
#pragma unroll
  for (int j = 0; j < 8; ++j) {
#pragma unroll
    for (int nt = 0; nt < 4; nt++)
#pragma unroll
      for (int r = 0; r < 4; r++)
        u.E[wm][q * 4 + r][wn * 64 + nt * 16 + cl] = acc[j][nt][r];
    __syncthreads();
    const size_t rg = (size_t)(m_base + (eb * 8 + j) * 16 + erow);
#pragma unroll
    for (int jo = 0; jo < 4; jo++) {
      const int cc = (ecs + 16 * jo) * 4;
      float4 e = *(const float4*)&u.E[eb][erow][cc];
      if constexpr (BIAS) {
        const float4 bb = *(const float4*)(bias + n_base + cc);
        e.x += bb.x; e.y += bb.y; e.z += bb.z; e.w += bb.w;
        *(float4*)((float*)Cout + rg * NOUT + n_base + cc) = e;
      } else {
        half4 hv;
        hv[0] = (_Float16)e.x; hv[1] = (_Float16)e.y;
        hv[2] = (_Float16)e.z; hv[3] = (_Float16)e.w;
        *(half4*)((_Float16*)Cout + rg * NOUT + n_base + cc) = hv;
      }
    }
    __syncthreads();
  }
}

// ---------------------------------------------------------------------------
// Windowed attention: one block per (head h, window b). W=64, hd=64.
// QKV rows: token = b*64+w; cols: q=h*64+e, k=512+h*64+e, v=1024+h*64+e.
// Q/K staged in fragment order: band (16 rows) x 8 chunks; chunk (r,c) of a
// band at slot c*16 + r  ->  fragment reads are band_base + lane*16.
// ---------------------------------------------------------------------------
__global__ __launch_bounds__(256, 3) void attn_win(const _Float16* __restrict__ QKV,
                                                   _Float16* __restrict__ Out) {
  __shared__ _Float16 Qs[4096];
  __shared__ _Float16 Ks[4096];
  __shared__ _Float16 Vt[64][72];   // V transposed: Vt[e][j], padded rows
  __shared__ _Float16 Ps[64][72];   // softmax probs
  __shared__ _Float16 Os[64][72];   // output staging
  const int h = blockIdx.x, b = blockIdx.y;
  const int t = threadIdx.x;
  const int lane = t & 63, wid = t >> 6;
  const int cl = lane & 15, q = lane >> 4;

  // ---- stage Q,K (async, fragment order) and V (manual transpose) ----
  {
    // slot s -> band = s>>7 (16 rows), chunk c = (s>>4)&7, row r = s&15
    const int s0 = t, s1 = t + 256;
    const int r0 = ((s0 >> 7) << 4) | (s0 & 15), ch0 = (s0 >> 4) & 7;
    const int r1 = ((s1 >> 7) << 4) | (s1 & 15), ch1 = (s1 >> 4) & 7;
    const _Float16* g0 = QKV + (size_t)(b * 64 + r0) * 1536 + h * 64 + ch0 * 8;
    const _Float16* g1 = QKV + (size_t)(b * 64 + r1) * 1536 + h * 64 + ch1 * 8;
    GLDS16(g0,       (char*)Qs + s0 * 16);
    GLDS16(g1,       (char*)Qs + s1 * 16);
    GLDS16(g0 + 512, (char*)Ks + s0 * 16);
    GLDS16(g1 + 512, (char*)Ks + s1 * 16);

    const int vj = t & 63, vp = t >> 6;   // row j of V, 16-half chunk vp
    const _Float16* vsrc = QKV + (size_t)(b * 64 + vj) * 1536 + 1024 + h * 64 + vp * 16;
    half8 v0 = *(const half8*)vsrc;
    half8 v1 = *(const half8*)(vsrc + 8);
#pragma unroll
    for (int i = 0; i < 8; i++) Vt[vp * 16 + i][vj] = v0[i];
#pragma unroll
    for (int i = 0; i < 8; i++) Vt[vp * 16 + 8 + i][vj] = v1[i];
  }
  __syncthreads();

  const int m0 = wid * 16;      // wave's 16 query rows
  const int lane8 = lane * 8;   // fragment offset in halves within a band

  // ---- S = Q K^T ----
  f32x4 s[4] = {};
#pragma unroll
  for (int ks = 0; ks < 2; ks++) {
    half8 a = *(const half8*)(Qs + wid * 1024 + ks * 512 + lane8);
#pragma unroll
    for (int nt = 0; nt < 4; nt++) {
      half8 bb = *(const half8*)(Ks + nt * 1024 + ks * 512 + lane8);
      s[nt] = __builtin_amdgcn_mfma_f32_16x16x32_f16(a, bb, s[nt], 0, 0, 0);
    }
  }

  // ---- softmax over 64 keys per row (row=q*4+r, keys spread over cl x nt) ----
  constexpr float SC = 0.125f * 1.44269504088896340736f;  // scale * log2(e)
#pragma unroll
  for (int r = 0; r < 4; r++) {
    float mx = fmaxf(fmaxf(s[0][r], s[1][r]), fmaxf(s[2][r], s[3][r]));
    mx = fmaxf(mx, __shfl_xor(mx, 1));
    mx = fmaxf(mx, __shfl_xor(mx, 2));
    mx = fmaxf(mx, __shfl_xor(mx, 4));
    mx = fmaxf(mx, __shfl_xor(mx, 8));
    float e[4], ssum = 0.f;
#pragma unroll
    for (int nt = 0; nt < 4; nt++) { e[nt] = exp2f((s[nt][r] - mx) * SC); ssum += e[nt]; }
    ssum += __shfl_xor(ssum, 1);
    ssum += __shfl_xor(ssum, 2);
    ssum += __shfl_xor(ssum, 4);
    ssum += __shfl_xor(ssum, 8);
    float inv = 1.f / ssum;
    const int row = m0 + q * 4 + r;
#pragma unroll
    for (int nt = 0; nt < 4; nt++) Ps[row][nt * 16 + cl] = (_Float16)(e[nt] * inv);
  }
  __syncthreads();

  // ---- O = P V  (a: Ps rows; b: Vt rows = V columns; 72-pad rotates groups) ----
  f32x4 o[4] = {};
#pragma unroll
  for (int ks = 0; ks < 2; ks++) {
    half8 a = *(const half8*)&Ps[m0 + cl][ks * 32 + q * 8];
#pragma unroll
    for (int nt = 0; nt < 4; nt++) {
      half8 bb = *(const half8*)&Vt[nt * 16 + cl][ks * 32 + q * 8];
      o[nt] = __builtin_amdgcn_mfma_f32_16x16x32_f16(a, bb, o[nt], 0, 0, 0);
    }
  }
#pragma unroll
  for (int nt = 0; nt < 4; nt++)
#pragma unroll
    for (int r = 0; r < 4; r++)
      Os[m0 + q * 4 + r][nt * 16 + cl] = (_Float16)o[nt][r];
  __syncthreads();

  // ---- coalesced write-out ----
  {
    const int row = t >> 2, cs = t & 3;
    half8 h0 = *(const half8*)&Os[row][cs * 16];
    half8 h1 = *(const half8*)&Os[row][cs * 16 + 8];
    _Float16* dst = Out + (size_t)(b * 64 + row) * 512 + h * 64 + cs * 16;
    *(half8*)dst = h0;
    *((half8*)dst + 1) = h1;
  }
}

// ---------------------------------------------------------------------------
extern "C" void kernel_launch(void* const* d_in, const int* in_sizes, int n_in,
                              void* d_out, int out_size, void* d_ws, size_t ws_size,
                              hipStream_t stream) {
  const float* x      = (const float*)d_in[0];   // 16*4096*512
  const float* qkv_w  = (const float*)d_in[1];   // 1536*512
  const float* proj_w = (const float*)d_in[2];   // 512*512
  const float* proj_b = (const float*)d_in[3];   // 512
  float* out = (float*)d_out;

  char* ws = (char*)d_ws;
  _Float16* QKVh = (_Float16*)ws;                 // 65536*1536 fp16 = 201,326,592 B
  _Float16* Xh   = (_Float16*)(ws + 201326592);   // 65536*512 fp16 = 67,108,864 B
  _Float16* Outh = Xh;                            // alias: Xh dead after qkv_gemm
  _Float16* Wq   = (_Float16*)(ws + 268435456);   // 1536*512 fp16
  _Float16* Wp   = (_Float16*)(ws + 270008320);   // 512*512 fp16

  cvt_f32_f16<<<16384, 256, 0, stream>>>(x, Xh, 16 * 4096 * 512);
  cvt_f32_f16<<<384, 256, 0, stream>>>(qkv_w, Wq, 1536 * 512);
  cvt_f32_f16<<<128, 256, 0, stream>>>(proj_w, Wp, 512 * 512);
  gemm_bt<1536, 6, false><<<1536, 512, 0, stream>>>(Xh, Wq, nullptr, QKVh);
  attn_win<<<dim3(8, 1024), 256, 0, stream>>>(QKVh, Outh);
  gemm_bt<512, 2, true><<<512, 512, 0, stream>>>(Outh, Wp, proj_b, out);
}